// Round 12
// baseline (1409.926 us; speedup 1.0000x reference)
//
#include <hip/hip_runtime.h>
#include <hip/hip_fp8.h>
#include <stdint.h>

#define NN 50000
#define NE 800000
#define NBLK 196   // ceil(NN/256)

typedef float f32x4 __attribute__((ext_vector_type(4)));
typedef short s16x8 __attribute__((ext_vector_type(8)));

__device__ __forceinline__ float bf2f(unsigned short u) {
    union { unsigned int i; float f; } v; v.i = ((unsigned int)u) << 16; return v.f;
}
__device__ __forceinline__ unsigned short f2bf(float x) {
    union { float f; unsigned int i; } v; v.f = x;
    unsigned int r = v.i + 0x7FFFu + ((v.i >> 16) & 1u);
    return (unsigned short)(r >> 16);
}
__device__ __forceinline__ unsigned char f2fp8(float x) {
    __hip_fp8_e4m3 t(x);
    return (unsigned char)t.__x;
}
__device__ __forceinline__ float fp82f(unsigned char u) {
    __hip_fp8_e4m3 t;
    t.__x = (__hip_fp8_storage_t)u;
    return (float)t;
}

// ---------------- graph preprocessing ----------------

__global__ void k_deg(const int* __restrict__ src, const int* __restrict__ dst,
                      int* __restrict__ dego, int* __restrict__ degi) {
    int e = blockIdx.x * 256 + threadIdx.x;
    if (e < NE) {
        atomicAdd(&dego[src[e]], 1);
        atomicAdd(&degi[dst[e]], 1);
    }
}

__global__ void k_scanA(const int* __restrict__ deg, int* __restrict__ incl,
                        int* __restrict__ bsum) {
    __shared__ int sm[256];
    int t = threadIdx.x, i = blockIdx.x * 256 + t;
    int v = (i < NN) ? deg[i] : 0;
    sm[t] = v;
    __syncthreads();
#pragma unroll
    for (int off = 1; off < 256; off <<= 1) {
        int tv = (t >= off) ? sm[t - off] : 0;
        __syncthreads();
        sm[t] += tv;
        __syncthreads();
    }
    if (i < NN) incl[i] = sm[t];
    if (t == 255) bsum[blockIdx.x] = sm[255];
}

__global__ void k_scanB(const int* __restrict__ bsum, int* __restrict__ boff,
                        int* __restrict__ row_ptr) {
    __shared__ int sm[256];
    int t = threadIdx.x;
    int v = (t < NBLK) ? bsum[t] : 0;
    sm[t] = v;
    __syncthreads();
#pragma unroll
    for (int off = 1; off < 256; off <<= 1) {
        int tv = (t >= off) ? sm[t - off] : 0;
        __syncthreads();
        sm[t] += tv;
        __syncthreads();
    }
    if (t < NBLK) boff[t] = sm[t] - v;  // exclusive
    if (t == 255) row_ptr[NN] = sm[255];
}

__global__ void k_scanC(const int* __restrict__ dego, const int* __restrict__ degi,
                        const int* __restrict__ incl, const int* __restrict__ boff,
                        int* __restrict__ row_ptr, int* __restrict__ cursor,
                        float* __restrict__ ns, float* __restrict__ nd) {
    int i = blockIdx.x * 256 + threadIdx.x;
    if (i < NN) {
        int ex = boff[blockIdx.x] + incl[i] - degi[i];
        row_ptr[i] = ex;
        cursor[i] = ex;
        ns[i] = dego[i] > 0 ? rsqrtf((float)dego[i]) : 0.f;
        nd[i] = degi[i] > 0 ? rsqrtf((float)degi[i]) : 0.f;
    }
}

__global__ void k_fill(const int* __restrict__ src, const int* __restrict__ dst,
                       const float* __restrict__ ns,
                       int* __restrict__ cursor, int* __restrict__ col_src,
                       float* __restrict__ ewt) {
    int e = blockIdx.x * 256 + threadIdx.x;
    if (e < NE) {
        int s = src[e];
        int slot = atomicAdd(&cursor[dst[e]], 1);
        col_src[slot] = s;
        ewt[slot] = ns[s];
    }
}

// ---------------- weight packing: fragment-stream order (1-term bf16) ----------------
// Granule g(r,kb) = (r>>4)*64+kb*16+(r&15); short index ((cb*T+t)*512+g)*8+e.

__global__ void k_packw(const float* __restrict__ W, unsigned short* __restrict__ out,
                        int K, int N, int ngran) {
    int gid = blockIdx.x * 256 + threadIdx.x;
    if (gid >= ngran) return;
    int T512 = (K >> 5) << 9;
    int cb = gid / T512, rem = gid - cb * T512;
    int t = rem >> 9, g = rem & 511;
    int r = ((g >> 6) << 4) | (g & 15);
    int kb = (g >> 4) & 3;
    int n = cb * 128 + r;
    int k = t * 32 + kb * 8;
    unsigned short vals[8];
#pragma unroll
    for (int e = 0; e < 8; ++e)
        vals[e] = f2bf(W[(size_t)(k + e) * N + n]);
    *(ushort4*)(out + (size_t)gid * 8) = make_ushort4(vals[0], vals[1], vals[2], vals[3]);
    *(ushort4*)(out + (size_t)gid * 8 + 4) = make_ushort4(vals[4], vals[5], vals[6], vals[7]);
}

struct QkvPtrs { const float* w[9]; unsigned short* out; };

__global__ void k_packqkv(QkvPtrs P) {
    int layer = blockIdx.y;
    int gid = blockIdx.x * 256 + threadIdx.x;       // 0..24575
    int cb = gid >> 12, rem = gid & 4095;           // T*512 = 4096 (T=8)
    int t = rem >> 9, g = rem & 511;
    int r = ((g >> 6) << 4) | (g & 15);
    int kb = (g >> 4) & 3;
    int n = cb * 128 + r;
    int which = n >> 8, nl = n & 255;
    int k = t * 32 + kb * 8;
    const float* W = P.w[layer * 3 + which];
    unsigned short vals[8];
#pragma unroll
    for (int e = 0; e < 8; ++e)
        vals[e] = f2bf(W[(size_t)(k + e) * 256 + nl]);
    size_t o = ((size_t)layer * 24576 + gid) * 8;
    *(ushort4*)(P.out + o) = make_ushort4(vals[0], vals[1], vals[2], vals[3]);
    *(ushort4*)(P.out + o + 4) = make_ushort4(vals[4], vals[5], vals[6], vals[7]);
}

struct BiasPtrs { const float* b[9]; float* dst; };

__global__ void k_bcat(BiasPtrs P) {
    int m = blockIdx.x;
    int layer = m / 3, which = m - layer * 3;
    P.dst[layer * 768 + which * 256 + (int)threadIdx.x] = P.b[m][threadIdx.x];
}

__global__ void k_cvt(const float* __restrict__ in, unsigned short* __restrict__ ob, int n4) {
    int i = blockIdx.x * 256 + threadIdx.x;
    if (i < n4) {
        float4 v = ((const float4*)in)[i];
        ushort4 o;
        o.x = f2bf(v.x); o.y = f2bf(v.y); o.z = f2bf(v.z); o.w = f2bf(v.w);
        ((ushort4*)ob)[i] = o;
    }
}

// ---------------- GCN propagate: y[d] = nd[d] * sum ewt[e] * x[src[e]] ----------------
// x fp8 e4m3 [NN,256] (256B rows); y bf16 [NN,256]. Lane-split: lanes 0-31
// even-slot edges, 32-63 odd; each lane 8 cols via one 8B load.

__global__ void k_prop(const unsigned char* __restrict__ x8,
                       const int* __restrict__ row_ptr, const int* __restrict__ col_src,
                       const float* __restrict__ ewt, const float* __restrict__ ndv,
                       unsigned short* __restrict__ y) {
    int w = (int)((blockIdx.x * 256 + threadIdx.x) >> 6);
    if (w >= NN) return;
    int lane = threadIdx.x & 63;
    int half = lane >> 5;
    int c = (lane & 31) * 8;      // byte/dim offset
    float a[8] = {};
    int e0 = row_ptr[w], e1 = row_ptr[w + 1];
    int p = e0;
    for (; p + 4 <= e1; p += 4) {
        int pa = p + half, pb = p + 2 + half;
        int sa = col_src[pa], sb = col_src[pb];
        float wa = ewt[pa], wb = ewt[pb];
        uint2 va = *(const uint2*)(x8 + (size_t)sa * 256 + c);
        uint2 vb = *(const uint2*)(x8 + (size_t)sb * 256 + c);
        const unsigned char* ua = (const unsigned char*)&va;
        const unsigned char* ub = (const unsigned char*)&vb;
#pragma unroll
        for (int i = 0; i < 8; ++i)
            a[i] += wa * fp82f(ua[i]) + wb * fp82f(ub[i]);
    }
    if (p + 2 <= e1) {
        int pa = p + half;
        int sa = col_src[pa];
        float wa = ewt[pa];
        uint2 va = *(const uint2*)(x8 + (size_t)sa * 256 + c);
        const unsigned char* ua = (const unsigned char*)&va;
#pragma unroll
        for (int i = 0; i < 8; ++i) a[i] += wa * fp82f(ua[i]);
        p += 2;
    }
    if (p < e1 && half == 0) {
        int sa = col_src[p];
        float wa = ewt[p];
        uint2 va = *(const uint2*)(x8 + (size_t)sa * 256 + c);
        const unsigned char* ua = (const unsigned char*)&va;
#pragma unroll
        for (int i = 0; i < 8; ++i) a[i] += wa * fp82f(ua[i]);
    }
#pragma unroll
    for (int i = 0; i < 8; ++i) a[i] += __shfl_xor(a[i], 32);
    if (lane < 32) {
        float sc = ndv[w];
        unsigned short us[8];
#pragma unroll
        for (int i = 0; i < 8; ++i) us[i] = f2bf(a[i] * sc);
        *(uint4*)(y + (size_t)w * 256 + c) = *(const uint4*)us;
    }
}

// ---------------- edge attention ----------------
// QKV row (1280B, 640 shorts): Q bf16 [0,256) shorts; K fp8 [512,768) bytes;
// V bf16 [384,640) shorts. One wave per dst; 16-lane group = head; lane = 4 dims.

__global__ void k_attn(const unsigned short* __restrict__ QKV,
                       const int* __restrict__ row_ptr, const int* __restrict__ col_src,
                       unsigned short* __restrict__ xo, unsigned char* __restrict__ xprop) {
    int w = (int)((blockIdx.x * 256 + threadIdx.x) >> 6);
    if (w >= NN) return;
    const unsigned char* QKV8 = (const unsigned char*)QKV;
    int lane = threadIdx.x & 63;
    int c = lane * 4;
    const ushort4 qu = *(const ushort4*)(QKV + (size_t)w * 640 + c);
    float q0 = bf2f(qu.x), q1 = bf2f(qu.y), q2 = bf2f(qu.z), q3 = bf2f(qu.w);
    float v0 = 0, v1 = 0, v2 = 0, v3 = 0, z = 0;
    int e0 = row_ptr[w], e1 = row_ptr[w + 1];
    int p = e0;
#define EDGE_K(s_, t_)                                                         \
    {                                                                          \
        unsigned int k4 = *(const unsigned int*)(QKV8 + (size_t)(s_) * 1280 + 512 + c); \
        t_ = q0 * fp82f(k4 & 0xFF) + q1 * fp82f((k4 >> 8) & 0xFF) +            \
             q2 * fp82f((k4 >> 16) & 0xFF) + q3 * fp82f(k4 >> 24);             \
    }
#define EDGE_V(s_, sc_)                                                        \
    {                                                                          \
        ushort4 vu = *(const ushort4*)(QKV + (size_t)(s_) * 640 + 384 + c);    \
        v0 += (sc_) * bf2f(vu.x); v1 += (sc_) * bf2f(vu.y);                    \
        v2 += (sc_) * bf2f(vu.z); v3 += (sc_) * bf2f(vu.w);                    \
        z += (sc_);                                                            \
    }
    for (; p + 4 <= e1; p += 4) {
        int s0 = col_src[p], s1 = col_src[p + 1], s2 = col_src[p + 2], s3 = col_src[p + 3];
        float t0, t1, t2, t3;
        EDGE_K(s0, t0) EDGE_K(s1, t1) EDGE_K(s2, t2) EDGE_K(s3, t3)
        t0 += __shfl_xor(t0, 1); t1 += __shfl_xor(t1, 1); t2 += __shfl_xor(t2, 1); t3 += __shfl_xor(t3, 1);
        t0 += __shfl_xor(t0, 2); t1 += __shfl_xor(t1, 2); t2 += __shfl_xor(t2, 2); t3 += __shfl_xor(t3, 2);
        t0 += __shfl_xor(t0, 4); t1 += __shfl_xor(t1, 4); t2 += __shfl_xor(t2, 4); t3 += __shfl_xor(t3, 4);
        t0 += __shfl_xor(t0, 8); t1 += __shfl_xor(t1, 8); t2 += __shfl_xor(t2, 8); t3 += __shfl_xor(t3, 8);
        float sc0 = __expf(fminf(fmaxf(t0 * 0.125f, -10.f), 10.f));
        float sc1 = __expf(fminf(fmaxf(t1 * 0.125f, -10.f), 10.f));
        float sc2 = __expf(fminf(fmaxf(t2 * 0.125f, -10.f), 10.f));
        float sc3 = __expf(fminf(fmaxf(t3 * 0.125f, -10.f), 10.f));
        EDGE_V(s0, sc0) EDGE_V(s1, sc1) EDGE_V(s2, sc2) EDGE_V(s3, sc3)
    }
    for (; p < e1; ++p) {
        int s0 = col_src[p];
        float t0;
        EDGE_K(s0, t0)
        t0 += __shfl_xor(t0, 1);
        t0 += __shfl_xor(t0, 2);
        t0 += __shfl_xor(t0, 4);
        t0 += __shfl_xor(t0, 8);
        float sc0 = __expf(fminf(fmaxf(t0 * 0.125f, -10.f), 10.f));
        EDGE_V(s0, sc0)
    }
#undef EDGE_K
#undef EDGE_V
    float inv = 1.f / (z + 1e-6f);
    float o0 = v0 * inv, o1 = v1 * inv, o2 = v2 * inv, o3 = v3 * inv;
    ushort4 o;
    o.x = f2bf(o0); o.y = f2bf(o1); o.z = f2bf(o2); o.w = f2bf(o3);
    *(ushort4*)(xo + (size_t)w * 768 + c) = o;
    if (xprop) {
        unsigned int pk = (unsigned int)f2fp8(o0) | ((unsigned int)f2fp8(o1) << 8) |
                          ((unsigned int)f2fp8(o2) << 16) | ((unsigned int)f2fp8(o3) << 24);
        *(unsigned int*)(xprop + (size_t)w * 256 + c) = pk;
    }
}

// ---------------- bf16 1-term GEMM: out = relu(A @ W + b) ----------------
// A row-major bf16; B packed bf16 fragment-stream. Per buffer (16KB):
// A swizzled granules [0,8192)B, B linear [8192,16384)B.
// A addr swizzle: abyte(g) = 16g ^ (((g>>4)&3)<<5). Write window
// W=(r&7)^(2kb) and read window W=(lane^(kg<<1))&7 are both all-distinct
// per 8 consecutive lanes -> conflict-free both sides. B linear both sides.
// LDS 32KB -> 5 blocks/CU. OMODE 0: bf16 out. OMODE 1: fp8 out [M,256].
// OMODE 2: QKV row 1280B = Q bf16 | K fp8 | V bf16.

template <int NC, int OMODE>
__global__ __launch_bounds__(256, 5) void k_gemm(
    const unsigned short* __restrict__ A, int lda,
    const unsigned short* __restrict__ Bpk,
    const float* __restrict__ bias,
    void* __restrict__ Cout, int ldc, int M, int K) {
    const int P = (M + 127) >> 7;
    const int xcd = blockIdx.x & 7;
    const int j = blockIdx.x >> 3;
    const int ck = (P >> 3) + ((xcd < (P & 7)) ? 1 : 0);
    if (j >= NC * ck) return;
    const int brow = ((j / NC) * 8 + xcd) * 128;
    const int bcol = (j % NC) * 128;
    const int T = K >> 5;

    __shared__ unsigned short smem[16384];   // 32KB: 2 bufs x 8192 shorts

    const int tid = threadIdx.x;
    const int lane = tid & 63;
    const int wid = tid >> 6;
    const int wm = wid & 1, wn = wid >> 1;
    const int fr = lane & 15, kg = lane >> 4;

    const int r0 = tid >> 2, kb = tid & 3;
    const int gr0 = brow + r0, gr1 = gr0 + 64;
    const int ga0 = ((r0 >> 4) << 6) | (kb << 4) | (r0 & 15);
    const int aw0 = (ga0 * 16) ^ (kb << 5);            // swizzled byte addr
    const int aw1 = ((ga0 + 256) * 16) ^ (kb << 5);
    const size_t aoff0 = (size_t)gr0 * lda + kb * 8;
    const size_t aoff1 = (size_t)gr1 * lda + kb * 8;
    const unsigned short* bstream = Bpk + (size_t)(bcol >> 7) * T * 4096;

    f32x4 acc[4][4] = {};
    uint4 av0, av1, bh0v, bh1v;

#define GLOAD(t_) {                                                            \
    const int k0_ = (t_) << 5;                                                 \
    av0 = make_uint4(0, 0, 0, 0); av1 = make_uint4(0, 0, 0, 0);                \
    if (gr0 < M) av0 = *(const uint4*)(A + aoff0 + k0_);                       \
    if (gr1 < M) av1 = *(const uint4*)(A + aoff1 + k0_);                       \
    const unsigned short* bs_ = bstream + (size_t)(t_) * 4096;                 \
    bh0v = *(const uint4*)(bs_ + tid * 8);                                     \
    bh1v = *(const uint4*)(bs_ + 2048 + tid * 8); }

#define LWRITE(b_) {                                                           \
    char* ab_ = (char*)smem + (b_) * 16384;                                    \
    *(uint4*)(ab_ + aw0) = av0;                                                \
    *(uint4*)(ab_ + aw1) = av1;                                                \
    unsigned short* sb_ = smem + (b_) * 8192 + 4096;                           \
    *(uint4*)(sb_ + tid * 8) = bh0v;                                           \
    *(uint4*)(sb_ + 2048 + tid * 8) = bh1v; }

    GLOAD(0)
    LWRITE(0)
    for (int t = 0; t < T; ++t) {
        __syncthreads();
        if (t + 1 < T) { GLOAD(t + 1) }
        char* ab = (char*)smem + (t & 1) * 16384;
        unsigned short* sb = smem + (t & 1) * 8192 + 4096;
        s16x8 a[4], bh[4];
#pragma unroll
        for (int f = 0; f < 4; ++f) {
            a[f]  = *(const s16x8*)(ab + ((((wm * 4 + f) * 64 + lane) * 16) ^ (kg << 5)));
            bh[f] = *(const s16x8*)(sb + ((wn * 4 + f) * 64 + lane) * 8);
        }
#pragma unroll
        for (int i = 0; i < 4; ++i)
#pragma unroll
            for (int jj = 0; jj < 4; ++jj)
                acc[i][jj] = __builtin_amdgcn_mfma_f32_16x16x32_bf16(a[i], bh[jj], acc[i][jj], 0, 0, 0);
        if (t + 1 < T) { LWRITE((t + 1) & 1) }
    }
#undef GLOAD
#undef LWRITE

#pragma unroll
    for (int i = 0; i < 4; ++i) {
#pragma unroll
        for (int jj = 0; jj < 4; ++jj) {
            int colG = bcol + wn * 64 + jj * 16 + fr;
            float bb = bias[colG];
#pragma unroll
            for (int r = 0; r < 4; ++r) {
                int row = brow + wm * 64 + i * 16 + kg * 4 + r;
                if (row < M) {
                    float v = fmaxf(acc[i][jj][r] + bb, 0.f);
                    if (OMODE == 0) {
                        ((unsigned short*)Cout)[(size_t)row * ldc + colG] = f2bf(v);
                    } else if (OMODE == 1) {
                        ((unsigned char*)Cout)[(size_t)row * 256 + colG] = f2fp8(v);
                    } else {
                        if (colG < 256)
                            ((unsigned short*)Cout)[(size_t)row * 640 + colG] = f2bf(v);
                        else if (colG < 512)
                            ((unsigned char*)Cout)[(size_t)row * 1280 + 512 + (colG - 256)] = f2fp8(v);
                        else
                            ((unsigned short*)Cout)[(size_t)row * 640 + 384 + (colG - 512)] = f2bf(v);
                    }
                }
            }
        }
    }
}

// ---------------- final row-dot + sigmoid ----------------

__global__ void k_final(const unsigned short* __restrict__ h2, const float* __restrict__ W3,
                        const float* __restrict__ b3, float* __restrict__ out) {
    int w = (int)((blockIdx.x * 256 + threadIdx.x) >> 6);
    if (w >= NN) return;
    int lane = threadIdx.x & 63;
    ushort4 hu = *(const ushort4*)(h2 + (size_t)w * 256 + lane * 4);
    float4 ww = *(const float4*)(W3 + lane * 4);
    float p = bf2f(hu.x) * ww.x + bf2f(hu.y) * ww.y + bf2f(hu.z) * ww.z + bf2f(hu.w) * ww.w;
    p += __shfl_xor(p, 1);
    p += __shfl_xor(p, 2);
    p += __shfl_xor(p, 4);
    p += __shfl_xor(p, 8);
    p += __shfl_xor(p, 16);
    p += __shfl_xor(p, 32);
    if (lane == 0) out[w] = 1.f / (1.f + __expf(-(p + b3[0])));
}

__global__ void k_sent(float* __restrict__ out) {
    int i = blockIdx.x * 256 + threadIdx.x;
    if (i < NN) out[i] = 0.5f;
}

// ---------------- launch ----------------

extern "C" void kernel_launch(void* const* d_in, const int* in_sizes, int n_in,
                              void* d_out, int out_size, void* d_ws, size_t ws_size,
                              hipStream_t stream) {
    const float* features = (const float*)d_in[0];
    const int* src = (const int*)d_in[1];
    const int* dst = (const int*)d_in[2];
    const float* Wm = (const float*)d_in[4];
    const float* bm = (const float*)d_in[5];
    const float* W1 = (const float*)d_in[24];
    const float* b1 = (const float*)d_in[25];
    const float* W2 = (const float*)d_in[26];
    const float* b2 = (const float*)d_in[27];
    const float* W3 = (const float*)d_in[28];
    const float* b3 = (const float*)d_in[29];
    float* out = (float*)d_out;

    char* ws = (char*)d_ws;
    size_t off = 0;
    auto alloc = [&](size_t b) -> void* {
        void* p = ws + off;
        off = (off + b + 255) & ~(size_t)255;
        return p;
    };

    int* deg_o = (int*)alloc(NN * 4);
    int* deg_i = (int*)alloc(NN * 4);
    int* row_ptr = (int*)alloc((NN + 1) * 4);
    int* cursor = (int*)alloc(NN * 4);
    int* col_src = (int*)alloc((size_t)NE * 4);
    float* ewt = (float*)alloc((size_t)NE * 4);
    float* ns = (float*)alloc(NN * 4);
    float* nd = (float*)alloc(NN * 4);
    int* incl = (int*)alloc(NN * 4);
    int* bsum = (int*)alloc(NBLK * 4);
    int* boff = (int*)alloc(NBLK * 4);

    unsigned short* Wmt = (unsigned short*)alloc((size_t)256 * 256 * 2);
    unsigned short* Wqkvt = (unsigned short*)alloc((size_t)3 * 768 * 256 * 2);
    unsigned short* W1t = (unsigned short*)alloc((size_t)512 * 768 * 2);
    unsigned short* W2t = (unsigned short*)alloc((size_t)256 * 512 * 2);
    float* bqkv = (float*)alloc(3 * 768 * 4);

    unsigned short* fbuf = (unsigned short*)alloc((size_t)NN * 256 * 2);     // 25.6 MB
    unsigned short* QKVb = (unsigned short*)alloc((size_t)NN * 640 * 2);     // 64 MB
    unsigned short* y = (unsigned short*)alloc((size_t)NN * 256 * 2);        // 25.6 MB
    unsigned short* xcat = (unsigned short*)alloc((size_t)NN * 768 * 2);     // 76.8 MB
    unsigned char* x0f8 = (unsigned char*)alloc((size_t)NN * 256);           // 12.8 MB
    unsigned char* xprop = (unsigned char*)alloc((size_t)NN * 256);          // 12.8 MB

    unsigned short* h1 = QKVb;    // [NN,512] bf16 = 51.2MB <= 64MB; QKVb dead after attn3
    unsigned short* h2 = y;       // [NN,256]; y dead after layer-3 QKV gemm

    (void)in_sizes; (void)n_in; (void)out_size;

    if (off > ws_size) {
        k_sent<<<(NN + 255) / 256, 256, 0, stream>>>(out);
        return;
    }

    hipMemsetAsync(deg_o, 0, (size_t)((char*)deg_i - (char*)deg_o) + NN * 4, stream);
    k_deg<<<(NE + 255) / 256, 256, 0, stream>>>(src, dst, deg_o, deg_i);
    k_scanA<<<NBLK, 256, 0, stream>>>(deg_i, incl, bsum);
    k_scanB<<<1, 256, 0, stream>>>(bsum, boff, row_ptr);
    k_scanC<<<NBLK, 256, 0, stream>>>(deg_o, deg_i, incl, boff, row_ptr, cursor, ns, nd);
    k_fill<<<(NE + 255) / 256, 256, 0, stream>>>(src, dst, ns, cursor, col_src, ewt);

    QkvPtrs qp;
    BiasPtrs bp;
    for (int l = 0; l < 3; ++l)
        for (int m = 0; m < 3; ++m) {
            qp.w[l * 3 + m] = (const float*)d_in[6 + l * 6 + m * 2];
            bp.b[l * 3 + m] = (const float*)d_in[7 + l * 6 + m * 2];
        }
    qp.out = Wqkvt;
    bp.dst = bqkv;
    k_packqkv<<<dim3(96, 3), 256, 0, stream>>>(qp);
    k_bcat<<<9, 256, 0, stream>>>(bp);
    k_packw<<<32, 256, 0, stream>>>(Wm, Wmt, 256, 256, 8192);
    k_packw<<<192, 256, 0, stream>>>(W1, W1t, 768, 512, 49152);
    k_packw<<<64, 256, 0, stream>>>(W2, W2t, 512, 256, 16384);

    k_cvt<<<(NN * 64 + 255) / 256, 256, 0, stream>>>(features, fbuf, NN * 64);

    const int P8 = ((NN + 127) / 128 + 7) / 8;  // 49

    // x0 (fp8) = relu(features @ Wm + bm)
    k_gemm<2, 1><<<8 * 2 * P8, 256, 0, stream>>>(fbuf, 256, Wmt, bm, x0f8, 0, NN, 256);

    const unsigned char* xin = x0f8;
    for (int l = 0; l < 3; ++l) {
        k_prop<<<12500, 256, 0, stream>>>(xin, row_ptr, col_src, ewt, nd, y);
        k_gemm<6, 2><<<8 * 6 * P8, 256, 0, stream>>>(y, 256, Wqkvt + (size_t)l * 196608,
                                                     bqkv + l * 768, QKVb, 0, NN, 256);
        k_attn<<<12500, 256, 0, stream>>>(QKVb, row_ptr, col_src, xcat + 256 * l,
                                          l < 2 ? xprop : nullptr);
        xin = xprop;
    }

    // MLP head
    k_gemm<4, 0><<<8 * 4 * P8, 256, 0, stream>>>(xcat, 768, W1t, b1, h1, 512, NN, 768);
    k_gemm<2, 0><<<8 * 2 * P8, 256, 0, stream>>>(h1, 512, W2t, b2, h2, 256, NN, 512);
    k_final<<<12500, 256, 0, stream>>>(h2, W3, b3, out);
}

// Round 13
// 809.321 us; speedup vs baseline: 1.7421x; 1.7421x over previous
//
#include <hip/hip_runtime.h>
#include <hip/hip_fp8.h>
#include <stdint.h>

#define NN 50000
#define NE 800000
#define NBLK 196   // ceil(NN/256)

typedef float f32x4 __attribute__((ext_vector_type(4)));
typedef short s16x8 __attribute__((ext_vector_type(8)));

__device__ __forceinline__ float bf2f(unsigned short u) {
    union { unsigned int i; float f; } v; v.i = ((unsigned int)u) << 16; return v.f;
}
__device__ __forceinline__ unsigned short f2bf(float x) {
    union { float f; unsigned int i; } v; v.f = x;
    unsigned int r = v.i + 0x7FFFu + ((v.i >> 16) & 1u);
    return (unsigned short)(r >> 16);
}
__device__ __forceinline__ unsigned char f2fp8(float x) {
    __hip_fp8_e4m3 t(x);
    return (unsigned char)t.__x;
}
__device__ __forceinline__ float fp82f(unsigned char u) {
    __hip_fp8_e4m3 t;
    t.__x = (__hip_fp8_storage_t)u;
    return (float)t;
}

// ---------------- graph preprocessing ----------------

__global__ void k_deg(const int* __restrict__ src, const int* __restrict__ dst,
                      int* __restrict__ dego, int* __restrict__ degi) {
    int e = blockIdx.x * 256 + threadIdx.x;
    if (e < NE) {
        atomicAdd(&dego[src[e]], 1);
        atomicAdd(&degi[dst[e]], 1);
    }
}

__global__ void k_scanA(const int* __restrict__ deg, int* __restrict__ incl,
                        int* __restrict__ bsum) {
    __shared__ int sm[256];
    int t = threadIdx.x, i = blockIdx.x * 256 + t;
    int v = (i < NN) ? deg[i] : 0;
    sm[t] = v;
    __syncthreads();
#pragma unroll
    for (int off = 1; off < 256; off <<= 1) {
        int tv = (t >= off) ? sm[t - off] : 0;
        __syncthreads();
        sm[t] += tv;
        __syncthreads();
    }
    if (i < NN) incl[i] = sm[t];
    if (t == 255) bsum[blockIdx.x] = sm[255];
}

__global__ void k_scanB(const int* __restrict__ bsum, int* __restrict__ boff,
                        int* __restrict__ row_ptr) {
    __shared__ int sm[256];
    int t = threadIdx.x;
    int v = (t < NBLK) ? bsum[t] : 0;
    sm[t] = v;
    __syncthreads();
#pragma unroll
    for (int off = 1; off < 256; off <<= 1) {
        int tv = (t >= off) ? sm[t - off] : 0;
        __syncthreads();
        sm[t] += tv;
        __syncthreads();
    }
    if (t < NBLK) boff[t] = sm[t] - v;  // exclusive
    if (t == 255) row_ptr[NN] = sm[255];
}

__global__ void k_scanC(const int* __restrict__ dego, const int* __restrict__ degi,
                        const int* __restrict__ incl, const int* __restrict__ boff,
                        int* __restrict__ row_ptr, int* __restrict__ cursor,
                        float* __restrict__ ns, float* __restrict__ nd) {
    int i = blockIdx.x * 256 + threadIdx.x;
    if (i < NN) {
        int ex = boff[blockIdx.x] + incl[i] - degi[i];
        row_ptr[i] = ex;
        cursor[i] = ex;
        ns[i] = dego[i] > 0 ? rsqrtf((float)dego[i]) : 0.f;
        nd[i] = degi[i] > 0 ? rsqrtf((float)degi[i]) : 0.f;
    }
}

__global__ void k_fill(const int* __restrict__ src, const int* __restrict__ dst,
                       const float* __restrict__ ns,
                       int* __restrict__ cursor, int* __restrict__ col_src,
                       float* __restrict__ ewt) {
    int e = blockIdx.x * 256 + threadIdx.x;
    if (e < NE) {
        int s = src[e];
        int slot = atomicAdd(&cursor[dst[e]], 1);
        col_src[slot] = s;
        ewt[slot] = ns[s];
    }
}

// ---------------- weight packing: fragment-stream order (1-term bf16) ----------------
// Granule g(r,kb) = (r>>4)*64+kb*16+(r&15); short index ((cb*T+t)*512+g)*8+e.

__global__ void k_packw(const float* __restrict__ W, unsigned short* __restrict__ out,
                        int K, int N, int ngran) {
    int gid = blockIdx.x * 256 + threadIdx.x;
    if (gid >= ngran) return;
    int T512 = (K >> 5) << 9;
    int cb = gid / T512, rem = gid - cb * T512;
    int t = rem >> 9, g = rem & 511;
    int r = ((g >> 6) << 4) | (g & 15);
    int kb = (g >> 4) & 3;
    int n = cb * 128 + r;
    int k = t * 32 + kb * 8;
    unsigned short vals[8];
#pragma unroll
    for (int e = 0; e < 8; ++e)
        vals[e] = f2bf(W[(size_t)(k + e) * N + n]);
    *(ushort4*)(out + (size_t)gid * 8) = make_ushort4(vals[0], vals[1], vals[2], vals[3]);
    *(ushort4*)(out + (size_t)gid * 8 + 4) = make_ushort4(vals[4], vals[5], vals[6], vals[7]);
}

struct QkvPtrs { const float* w[9]; unsigned short* out; };

__global__ void k_packqkv(QkvPtrs P) {
    int layer = blockIdx.y;
    int gid = blockIdx.x * 256 + threadIdx.x;       // 0..24575
    int cb = gid >> 12, rem = gid & 4095;           // T*512 = 4096 (T=8)
    int t = rem >> 9, g = rem & 511;
    int r = ((g >> 6) << 4) | (g & 15);
    int kb = (g >> 4) & 3;
    int n = cb * 128 + r;
    int which = n >> 8, nl = n & 255;
    int k = t * 32 + kb * 8;
    const float* W = P.w[layer * 3 + which];
    unsigned short vals[8];
#pragma unroll
    for (int e = 0; e < 8; ++e)
        vals[e] = f2bf(W[(size_t)(k + e) * 256 + nl]);
    size_t o = ((size_t)layer * 24576 + gid) * 8;
    *(ushort4*)(P.out + o) = make_ushort4(vals[0], vals[1], vals[2], vals[3]);
    *(ushort4*)(P.out + o + 4) = make_ushort4(vals[4], vals[5], vals[6], vals[7]);
}

struct BiasPtrs { const float* b[9]; float* dst; };

__global__ void k_bcat(BiasPtrs P) {
    int m = blockIdx.x;
    int layer = m / 3, which = m - layer * 3;
    P.dst[layer * 768 + which * 256 + (int)threadIdx.x] = P.b[m][threadIdx.x];
}

__global__ void k_cvt(const float* __restrict__ in, unsigned short* __restrict__ ob, int n4) {
    int i = blockIdx.x * 256 + threadIdx.x;
    if (i < n4) {
        float4 v = ((const float4*)in)[i];
        ushort4 o;
        o.x = f2bf(v.x); o.y = f2bf(v.y); o.z = f2bf(v.z); o.w = f2bf(v.w);
        ((ushort4*)ob)[i] = o;
    }
}

// ---------------- GCN propagate: y[d] = nd[d] * sum ewt[e] * x[src[e]] ----------------
// x fp8 e4m3 [NN,256] (256B rows); y bf16 [NN,256]. Lane-split: lanes 0-31
// even-slot edges, 32-63 odd; each lane 8 cols via one 8B load.

__global__ void k_prop(const unsigned char* __restrict__ x8,
                       const int* __restrict__ row_ptr, const int* __restrict__ col_src,
                       const float* __restrict__ ewt, const float* __restrict__ ndv,
                       unsigned short* __restrict__ y) {
    int w = (int)((blockIdx.x * 256 + threadIdx.x) >> 6);
    if (w >= NN) return;
    int lane = threadIdx.x & 63;
    int half = lane >> 5;
    int c = (lane & 31) * 8;      // byte/dim offset
    float a[8] = {};
    int e0 = row_ptr[w], e1 = row_ptr[w + 1];
    int p = e0;
    for (; p + 4 <= e1; p += 4) {
        int pa = p + half, pb = p + 2 + half;
        int sa = col_src[pa], sb = col_src[pb];
        float wa = ewt[pa], wb = ewt[pb];
        uint2 va = *(const uint2*)(x8 + (size_t)sa * 256 + c);
        uint2 vb = *(const uint2*)(x8 + (size_t)sb * 256 + c);
        const unsigned char* ua = (const unsigned char*)&va;
        const unsigned char* ub = (const unsigned char*)&vb;
#pragma unroll
        for (int i = 0; i < 8; ++i)
            a[i] += wa * fp82f(ua[i]) + wb * fp82f(ub[i]);
    }
    if (p + 2 <= e1) {
        int pa = p + half;
        int sa = col_src[pa];
        float wa = ewt[pa];
        uint2 va = *(const uint2*)(x8 + (size_t)sa * 256 + c);
        const unsigned char* ua = (const unsigned char*)&va;
#pragma unroll
        for (int i = 0; i < 8; ++i) a[i] += wa * fp82f(ua[i]);
        p += 2;
    }
    if (p < e1 && half == 0) {
        int sa = col_src[p];
        float wa = ewt[p];
        uint2 va = *(const uint2*)(x8 + (size_t)sa * 256 + c);
        const unsigned char* ua = (const unsigned char*)&va;
#pragma unroll
        for (int i = 0; i < 8; ++i) a[i] += wa * fp82f(ua[i]);
    }
#pragma unroll
    for (int i = 0; i < 8; ++i) a[i] += __shfl_xor(a[i], 32);
    if (lane < 32) {
        float sc = ndv[w];
        unsigned short us[8];
#pragma unroll
        for (int i = 0; i < 8; ++i) us[i] = f2bf(a[i] * sc);
        *(uint4*)(y + (size_t)w * 256 + c) = *(const uint4*)us;
    }
}

// ---------------- edge attention ----------------
// QKV row (1280B, 640 shorts): Q bf16 [0,256) shorts; K fp8 [512,768) bytes;
// V bf16 [384,640) shorts. One wave per dst; 16-lane group = head; lane = 4 dims.

__global__ void k_attn(const unsigned short* __restrict__ QKV,
                       const int* __restrict__ row_ptr, const int* __restrict__ col_src,
                       unsigned short* __restrict__ xo, unsigned char* __restrict__ xprop) {
    int w = (int)((blockIdx.x * 256 + threadIdx.x) >> 6);
    if (w >= NN) return;
    const unsigned char* QKV8 = (const unsigned char*)QKV;
    int lane = threadIdx.x & 63;
    int c = lane * 4;
    const ushort4 qu = *(const ushort4*)(QKV + (size_t)w * 640 + c);
    float q0 = bf2f(qu.x), q1 = bf2f(qu.y), q2 = bf2f(qu.z), q3 = bf2f(qu.w);
    float v0 = 0, v1 = 0, v2 = 0, v3 = 0, z = 0;
    int e0 = row_ptr[w], e1 = row_ptr[w + 1];
    int p = e0;
#define EDGE_K(s_, t_)                                                         \
    {                                                                          \
        unsigned int k4 = *(const unsigned int*)(QKV8 + (size_t)(s_) * 1280 + 512 + c); \
        t_ = q0 * fp82f(k4 & 0xFF) + q1 * fp82f((k4 >> 8) & 0xFF) +            \
             q2 * fp82f((k4 >> 16) & 0xFF) + q3 * fp82f(k4 >> 24);             \
    }
#define EDGE_V(s_, sc_)                                                        \
    {                                                                          \
        ushort4 vu = *(const ushort4*)(QKV + (size_t)(s_) * 640 + 384 + c);    \
        v0 += (sc_) * bf2f(vu.x); v1 += (sc_) * bf2f(vu.y);                    \
        v2 += (sc_) * bf2f(vu.z); v3 += (sc_) * bf2f(vu.w);                    \
        z += (sc_);                                                            \
    }
    for (; p + 4 <= e1; p += 4) {
        int s0 = col_src[p], s1 = col_src[p + 1], s2 = col_src[p + 2], s3 = col_src[p + 3];
        float t0, t1, t2, t3;
        EDGE_K(s0, t0) EDGE_K(s1, t1) EDGE_K(s2, t2) EDGE_K(s3, t3)
        t0 += __shfl_xor(t0, 1); t1 += __shfl_xor(t1, 1); t2 += __shfl_xor(t2, 1); t3 += __shfl_xor(t3, 1);
        t0 += __shfl_xor(t0, 2); t1 += __shfl_xor(t1, 2); t2 += __shfl_xor(t2, 2); t3 += __shfl_xor(t3, 2);
        t0 += __shfl_xor(t0, 4); t1 += __shfl_xor(t1, 4); t2 += __shfl_xor(t2, 4); t3 += __shfl_xor(t3, 4);
        t0 += __shfl_xor(t0, 8); t1 += __shfl_xor(t1, 8); t2 += __shfl_xor(t2, 8); t3 += __shfl_xor(t3, 8);
        float sc0 = __expf(fminf(fmaxf(t0 * 0.125f, -10.f), 10.f));
        float sc1 = __expf(fminf(fmaxf(t1 * 0.125f, -10.f), 10.f));
        float sc2 = __expf(fminf(fmaxf(t2 * 0.125f, -10.f), 10.f));
        float sc3 = __expf(fminf(fmaxf(t3 * 0.125f, -10.f), 10.f));
        EDGE_V(s0, sc0) EDGE_V(s1, sc1) EDGE_V(s2, sc2) EDGE_V(s3, sc3)
    }
    for (; p < e1; ++p) {
        int s0 = col_src[p];
        float t0;
        EDGE_K(s0, t0)
        t0 += __shfl_xor(t0, 1);
        t0 += __shfl_xor(t0, 2);
        t0 += __shfl_xor(t0, 4);
        t0 += __shfl_xor(t0, 8);
        float sc0 = __expf(fminf(fmaxf(t0 * 0.125f, -10.f), 10.f));
        EDGE_V(s0, sc0)
    }
#undef EDGE_K
#undef EDGE_V
    float inv = 1.f / (z + 1e-6f);
    float o0 = v0 * inv, o1 = v1 * inv, o2 = v2 * inv, o3 = v3 * inv;
    ushort4 o;
    o.x = f2bf(o0); o.y = f2bf(o1); o.z = f2bf(o2); o.w = f2bf(o3);
    *(ushort4*)(xo + (size_t)w * 768 + c) = o;
    if (xprop) {
        unsigned int pk = (unsigned int)f2fp8(o0) | ((unsigned int)f2fp8(o1) << 8) |
                          ((unsigned int)f2fp8(o2) << 16) | ((unsigned int)f2fp8(o3) << 24);
        *(unsigned int*)(xprop + (size_t)w * 256 + c) = pk;
    }
}

// ---------------- bf16 1-term GEMM: out = relu(A @ W + b) ----------------
// A row-major bf16; B packed bf16 fragment-stream. Per buffer (16KB):
// A swizzled granules [0,8192)B, B linear [8192,16384)B.
// A addr swizzle: abyte(g) = 16g ^ (((g>>4)&3)<<5) -> conflict-free both sides.
// LDS 32KB. launch_bounds(256,4): 4 blocks/CU, VGPR cap 128 (acc=64 fits; the
// (256,5) variant capped VGPR at 48 and SPILLED acc to scratch: 625MB writes,
// MfmaUtil 5% -- R12 regression).
// OMODE 0: bf16 out. OMODE 1: fp8 out [M,256]. OMODE 2: QKV row 1280B.

template <int NC, int OMODE>
__global__ __launch_bounds__(256, 4) void k_gemm(
    const unsigned short* __restrict__ A, int lda,
    const unsigned short* __restrict__ Bpk,
    const float* __restrict__ bias,
    void* __restrict__ Cout, int ldc, int M, int K) {
    const int P = (M + 127) >> 7;
    const int xcd = blockIdx.x & 7;
    const int j = blockIdx.x >> 3;
    const int ck = (P >> 3) + ((xcd < (P & 7)) ? 1 : 0);
    if (j >= NC * ck) return;
    const int brow = ((j / NC) * 8 + xcd) * 128;
    const int bcol = (j % NC) * 128;
    const int T = K >> 5;

    __shared__ unsigned short smem[16384];   // 32KB: 2 bufs x 8192 shorts

    const int tid = threadIdx.x;
    const int lane = tid & 63;
    const int wid = tid >> 6;
    const int wm = wid & 1, wn = wid >> 1;
    const int fr = lane & 15, kg = lane >> 4;

    const int r0 = tid >> 2, kb = tid & 3;
    const int gr0 = brow + r0, gr1 = gr0 + 64;
    const int ga0 = ((r0 >> 4) << 6) | (kb << 4) | (r0 & 15);
    const int aw0 = (ga0 * 16) ^ (kb << 5);            // swizzled byte addr
    const int aw1 = ((ga0 + 256) * 16) ^ (kb << 5);
    const size_t aoff0 = (size_t)gr0 * lda + kb * 8;
    const size_t aoff1 = (size_t)gr1 * lda + kb * 8;
    const unsigned short* bstream = Bpk + (size_t)(bcol >> 7) * T * 4096;

    f32x4 acc[4][4] = {};
    uint4 av0, av1, bh0v, bh1v;

#define GLOAD(t_) {                                                            \
    const int k0_ = (t_) << 5;                                                 \
    av0 = make_uint4(0, 0, 0, 0); av1 = make_uint4(0, 0, 0, 0);                \
    if (gr0 < M) av0 = *(const uint4*)(A + aoff0 + k0_);                       \
    if (gr1 < M) av1 = *(const uint4*)(A + aoff1 + k0_);                       \
    const unsigned short* bs_ = bstream + (size_t)(t_) * 4096;                 \
    bh0v = *(const uint4*)(bs_ + tid * 8);                                     \
    bh1v = *(const uint4*)(bs_ + 2048 + tid * 8); }

#define LWRITE(b_) {                                                           \
    char* ab_ = (char*)smem + (b_) * 16384;                                    \
    *(uint4*)(ab_ + aw0) = av0;                                                \
    *(uint4*)(ab_ + aw1) = av1;                                                \
    unsigned short* sb_ = smem + (b_) * 8192 + 4096;                           \
    *(uint4*)(sb_ + tid * 8) = bh0v;                                           \
    *(uint4*)(sb_ + 2048 + tid * 8) = bh1v; }

    GLOAD(0)
    LWRITE(0)
    for (int t = 0; t < T; ++t) {
        __syncthreads();
        if (t + 1 < T) { GLOAD(t + 1) }
        char* ab = (char*)smem + (t & 1) * 16384;
        unsigned short* sb = smem + (t & 1) * 8192 + 4096;
        s16x8 a[4], bh[4];
#pragma unroll
        for (int f = 0; f < 4; ++f) {
            a[f]  = *(const s16x8*)(ab + ((((wm * 4 + f) * 64 + lane) * 16) ^ (kg << 5)));
            bh[f] = *(const s16x8*)(sb + ((wn * 4 + f) * 64 + lane) * 8);
        }
#pragma unroll
        for (int i = 0; i < 4; ++i)
#pragma unroll
            for (int jj = 0; jj < 4; ++jj)
                acc[i][jj] = __builtin_amdgcn_mfma_f32_16x16x32_bf16(a[i], bh[jj], acc[i][jj], 0, 0, 0);
        if (t + 1 < T) { LWRITE((t + 1) & 1) }
    }
#undef GLOAD
#undef LWRITE

#pragma unroll
    for (int i = 0; i < 4; ++i) {
#pragma unroll
        for (int jj = 0; jj < 4; ++jj) {
            int colG = bcol + wn * 64 + jj * 16 + fr;
            float bb = bias[colG];
#pragma unroll
            for (int r = 0; r < 4; ++r) {
                int row = brow + wm * 64 + i * 16 + kg * 4 + r;
                if (row < M) {
                    float v = fmaxf(acc[i][jj][r] + bb, 0.f);
                    if (OMODE == 0) {
                        ((unsigned short*)Cout)[(size_t)row * ldc + colG] = f2bf(v);
                    } else if (OMODE == 1) {
                        ((unsigned char*)Cout)[(size_t)row * 256 + colG] = f2fp8(v);
                    } else {
                        if (colG < 256)
                            ((unsigned short*)Cout)[(size_t)row * 640 + colG] = f2bf(v);
                        else if (colG < 512)
                            ((unsigned char*)Cout)[(size_t)row * 1280 + 512 + (colG - 256)] = f2fp8(v);
                        else
                            ((unsigned short*)Cout)[(size_t)row * 640 + 384 + (colG - 512)] = f2bf(v);
                    }
                }
            }
        }
    }
}

// ---------------- final row-dot + sigmoid ----------------

__global__ void k_final(const unsigned short* __restrict__ h2, const float* __restrict__ W3,
                        const float* __restrict__ b3, float* __restrict__ out) {
    int w = (int)((blockIdx.x * 256 + threadIdx.x) >> 6);
    if (w >= NN) return;
    int lane = threadIdx.x & 63;
    ushort4 hu = *(const ushort4*)(h2 + (size_t)w * 256 + lane * 4);
    float4 ww = *(const float4*)(W3 + lane * 4);
    float p = bf2f(hu.x) * ww.x + bf2f(hu.y) * ww.y + bf2f(hu.z) * ww.z + bf2f(hu.w) * ww.w;
    p += __shfl_xor(p, 1);
    p += __shfl_xor(p, 2);
    p += __shfl_xor(p, 4);
    p += __shfl_xor(p, 8);
    p += __shfl_xor(p, 16);
    p += __shfl_xor(p, 32);
    if (lane == 0) out[w] = 1.f / (1.f + __expf(-(p + b3[0])));
}

__global__ void k_sent(float* __restrict__ out) {
    int i = blockIdx.x * 256 + threadIdx.x;
    if (i < NN) out[i] = 0.5f;
}

// ---------------- launch ----------------

extern "C" void kernel_launch(void* const* d_in, const int* in_sizes, int n_in,
                              void* d_out, int out_size, void* d_ws, size_t ws_size,
                              hipStream_t stream) {
    const float* features = (const float*)d_in[0];
    const int* src = (const int*)d_in[1];
    const int* dst = (const int*)d_in[2];
    const float* Wm = (const float*)d_in[4];
    const float* bm = (const float*)d_in[5];
    const float* W1 = (const float*)d_in[24];
    const float* b1 = (const float*)d_in[25];
    const float* W2 = (const float*)d_in[26];
    const float* b2 = (const float*)d_in[27];
    const float* W3 = (const float*)d_in[28];
    const float* b3 = (const float*)d_in[29];
    float* out = (float*)d_out;

    char* ws = (char*)d_ws;
    size_t off = 0;
    auto alloc = [&](size_t b) -> void* {
        void* p = ws + off;
        off = (off + b + 255) & ~(size_t)255;
        return p;
    };

    int* deg_o = (int*)alloc(NN * 4);
    int* deg_i = (int*)alloc(NN * 4);
    int* row_ptr = (int*)alloc((NN + 1) * 4);
    int* cursor = (int*)alloc(NN * 4);
    int* col_src = (int*)alloc((size_t)NE * 4);
    float* ewt = (float*)alloc((size_t)NE * 4);
    float* ns = (float*)alloc(NN * 4);
    float* nd = (float*)alloc(NN * 4);
    int* incl = (int*)alloc(NN * 4);
    int* bsum = (int*)alloc(NBLK * 4);
    int* boff = (int*)alloc(NBLK * 4);

    unsigned short* Wmt = (unsigned short*)alloc((size_t)256 * 256 * 2);
    unsigned short* Wqkvt = (unsigned short*)alloc((size_t)3 * 768 * 256 * 2);
    unsigned short* W1t = (unsigned short*)alloc((size_t)512 * 768 * 2);
    unsigned short* W2t = (unsigned short*)alloc((size_t)256 * 512 * 2);
    float* bqkv = (float*)alloc(3 * 768 * 4);

    unsigned short* fbuf = (unsigned short*)alloc((size_t)NN * 256 * 2);     // 25.6 MB
    unsigned short* QKVb = (unsigned short*)alloc((size_t)NN * 640 * 2);     // 64 MB
    unsigned short* y = (unsigned short*)alloc((size_t)NN * 256 * 2);        // 25.6 MB
    unsigned short* xcat = (unsigned short*)alloc((size_t)NN * 768 * 2);     // 76.8 MB
    unsigned char* x0f8 = (unsigned char*)alloc((size_t)NN * 256);           // 12.8 MB
    unsigned char* xprop = (unsigned char*)alloc((size_t)NN * 256);          // 12.8 MB

    unsigned short* h1 = QKVb;    // [NN,512] bf16 = 51.2MB <= 64MB; QKVb dead after attn3
    unsigned short* h2 = y;       // [NN,256]; y dead after layer-3 QKV gemm

    (void)in_sizes; (void)n_in; (void)out_size;

    if (off > ws_size) {
        k_sent<<<(NN + 255) / 256, 256, 0, stream>>>(out);
        return;
    }

    hipMemsetAsync(deg_o, 0, (size_t)((char*)deg_i - (char*)deg_o) + NN * 4, stream);
    k_deg<<<(NE + 255) / 256, 256, 0, stream>>>(src, dst, deg_o, deg_i);
    k_scanA<<<NBLK, 256, 0, stream>>>(deg_i, incl, bsum);
    k_scanB<<<1, 256, 0, stream>>>(bsum, boff, row_ptr);
    k_scanC<<<NBLK, 256, 0, stream>>>(deg_o, deg_i, incl, boff, row_ptr, cursor, ns, nd);
    k_fill<<<(NE + 255) / 256, 256, 0, stream>>>(src, dst, ns, cursor, col_src, ewt);

    QkvPtrs qp;
    BiasPtrs bp;
    for (int l = 0; l < 3; ++l)
        for (int m = 0; m < 3; ++m) {
            qp.w[l * 3 + m] = (const float*)d_in[6 + l * 6 + m * 2];
            bp.b[l * 3 + m] = (const float*)d_in[7 + l * 6 + m * 2];
        }
    qp.out = Wqkvt;
    bp.dst = bqkv;
    k_packqkv<<<dim3(96, 3), 256, 0, stream>>>(qp);
    k_bcat<<<9, 256, 0, stream>>>(bp);
    k_packw<<<32, 256, 0, stream>>>(Wm, Wmt, 256, 256, 8192);
    k_packw<<<192, 256, 0, stream>>>(W1, W1t, 768, 512, 49152);
    k_packw<<<64, 256, 0, stream>>>(W2, W2t, 512, 256, 16384);

    k_cvt<<<(NN * 64 + 255) / 256, 256, 0, stream>>>(features, fbuf, NN * 64);

    const int P8 = ((NN + 127) / 128 + 7) / 8;  // 49

    // x0 (fp8) = relu(features @ Wm + bm)
    k_gemm<2, 1><<<8 * 2 * P8, 256, 0, stream>>>(fbuf, 256, Wmt, bm, x0f8, 0, NN, 256);

    const unsigned char* xin = x0f8;
    for (int l = 0; l < 3; ++l) {
        k_prop<<<12500, 256, 0, stream>>>(xin, row_ptr, col_src, ewt, nd, y);
        k_gemm<6, 2><<<8 * 6 * P8, 256, 0, stream>>>(y, 256, Wqkvt + (size_t)l * 196608,
                                                     bqkv + l * 768, QKVb, 0, NN, 256);
        k_attn<<<12500, 256, 0, stream>>>(QKVb, row_ptr, col_src, xcat + 256 * l,
                                          l < 2 ? xprop : nullptr);
        xin = xprop;
    }

    // MLP head
    k_gemm<4, 0><<<8 * 4 * P8, 256, 0, stream>>>(xcat, 768, W1t, b1, h1, 512, NN, 768);
    k_gemm<2, 0><<<8 * 2 * P8, 256, 0, stream>>>(h1, 512, W2t, b2, h2, 256, NN, 512);
    k_final<<<12500, 256, 0, stream>>>(h2, W3, b3, out);
}